// Round 7
// baseline (120.546 us; speedup 1.0000x reference)
//
#include <hip/hip_runtime.h>
#include <stdint.h>

typedef __bf16 bf16x8 __attribute__((ext_vector_type(8)));
typedef float  f32x4  __attribute__((ext_vector_type(4)));
typedef float  f32x16 __attribute__((ext_vector_type(16)));
typedef unsigned short u16;
typedef unsigned int   u32;

#define B_  2
#define S_  2048
#define H_  1024
#define NH_ 16
#define HD_ 64
#define KVB 32
#define QSCL 0.18033688011112042f  /* 0.125 * log2(e) */

__device__ __forceinline__ u16 f2bf(float f) {
  u32 u = __builtin_bit_cast(u32, f);
  return (u16)((u + 0x7FFFu + ((u >> 16) & 1u)) >> 16);
}
__device__ __forceinline__ float ex2(float x) { return __builtin_amdgcn_exp2f(x); }
__device__ __forceinline__ u32 cvtpk(float lo, float hi) {
  u32 r; asm("v_cvt_pk_bf16_f32 %0, %1, %2" : "=v"(r) : "v"(lo), "v"(hi)); return r;
}
__device__ __forceinline__ void gload_lds16(const u16* g, u16* lds) {
  __builtin_amdgcn_global_load_lds(
      (__attribute__((address_space(1))) void*)(void*)g,
      (__attribute__((address_space(3))) void*)lds, 16, 0, 0);
}

__global__ void cvt_all(const float* __restrict__ a, const float* __restrict__ b,
                        const float* __restrict__ c, u16* __restrict__ oa,
                        u16* __restrict__ ob, u16* __restrict__ oc) {
  int i = blockIdx.x * 256 + threadIdx.x;
  const float4* src; ushort4* dst; int j;
  if (i < 1048576)      { src = (const float4*)a; dst = (ushort4*)oa; j = i; }
  else if (i < 1835008) { src = (const float4*)b; dst = (ushort4*)ob; j = i - 1048576; }
  else                  { src = (const float4*)c; dst = (ushort4*)oc; j = i - 1835008; }
  const float4 v = src[j];
  ushort4 o;
  o.x = f2bf(v.x); o.y = f2bf(v.y); o.z = f2bf(v.z); o.w = f2bf(v.w);
  dst[j] = o;
}

// QKV: C = A[M,K] * W[N,K]^T + bias, scatter bf16 to q (pre-scaled) / k / vt.
__global__ __launch_bounds__(256, 2)
void gemm_qkv(const u16* __restrict__ A, const u16* __restrict__ W,
              const float* __restrict__ bias,
              u16* __restrict__ qb, u16* __restrict__ kb, u16* __restrict__ vtb,
              int M, int N, int K)
{
  __shared__ __align__(16) u16 As[128 * 32];
  __shared__ __align__(16) u16 Bs[128 * 32];
  const int tid = threadIdx.x;
  const int w = tid >> 6, l = tid & 63;
  const int lg = l >> 4, lr = l & 15;
  const int wr = w >> 1, wc = w & 1;
  const int tM = blockIdx.y * 128, tN = blockIdx.x * 128;

  f32x4 acc[4][4];
  const f32x4 z4 = {0.f, 0.f, 0.f, 0.f};
#pragma unroll
  for (int m = 0; m < 4; ++m)
#pragma unroll
    for (int n = 0; n < 4; ++n) acc[m][n] = z4;

  for (int k0 = 0; k0 < K; k0 += 32) {
    __syncthreads();
#pragma unroll
    for (int i = 0; i < 2; ++i) {
      const int ch = i * 256 + tid;
      const int row = ch >> 2, cc = (ch & 3) * 8;
      gload_lds16(A + (size_t)(tM + row) * K + k0 + cc, As + (size_t)(i * 256 + w * 64) * 8);
      gload_lds16(W + (size_t)(tN + row) * K + k0 + cc, Bs + (size_t)(i * 256 + w * 64) * 8);
    }
    __syncthreads();
    bf16x8 af[4], bw[4];
#pragma unroll
    for (int m = 0; m < 4; ++m)
      af[m] = *(const bf16x8*)&As[(wr * 64 + m * 16 + lr) * 32 + lg * 8];
#pragma unroll
    for (int n = 0; n < 4; ++n)
      bw[n] = *(const bf16x8*)&Bs[(wc * 64 + n * 16 + lr) * 32 + lg * 8];
#pragma unroll
    for (int m = 0; m < 4; ++m)
#pragma unroll
      for (int n = 0; n < 4; ++n)
        acc[m][n] = __builtin_amdgcn_mfma_f32_16x16x32_bf16(af[m], bw[n], acc[m][n], 0, 0, 0);
  }

#pragma unroll
  for (int n = 0; n < 4; ++n) {
    const int col = tN + wc * 64 + n * 16 + lr;
    const float bv = bias[col];
    const int t3 = col >> 10, rem = col & 1023;
    const int hh = rem >> 6, dd = rem & 63;
    const float sc = (t3 == 0) ? QSCL : 1.f;
    u16* dst = (t3 == 0) ? qb : (t3 == 1) ? kb : vtb;
#pragma unroll
    for (int m = 0; m < 4; ++m)
#pragma unroll
      for (int r = 0; r < 4; ++r) {
        const int row = tM + wr * 64 + m * 16 + lg * 4 + r;
        const int bb = row >> 11, ss = row & 2047;
        const u16 val = f2bf((acc[m][n][r] + bv) * sc);
        if (t3 < 2) dst[((size_t)(bb * NH_ + hh) * S_ + ss) * HD_ + dd] = val;
        else        dst[((size_t)(bb * NH_ + hh) * HD_ + dd) * S_ + ss] = val;
      }
  }
}

// Out-proj: C = A[M,K] * W[N,K]^T + bias, fp32 out. 128x64 tiles.
__global__ __launch_bounds__(256, 2)
void gemm_out(const u16* __restrict__ A, const u16* __restrict__ W,
              const float* __restrict__ bias, float* __restrict__ outf,
              int M, int N, int K)
{
  __shared__ __align__(16) u16 As[128 * 32];
  __shared__ __align__(16) u16 Bs[64 * 32];
  const int tid = threadIdx.x;
  const int w = tid >> 6, l = tid & 63;
  const int lg = l >> 4, lr = l & 15;
  const int tM = blockIdx.y * 128, tN = blockIdx.x * 64;

  f32x4 acc[2][4];
  const f32x4 z4 = {0.f, 0.f, 0.f, 0.f};
#pragma unroll
  for (int m = 0; m < 2; ++m)
#pragma unroll
    for (int n = 0; n < 4; ++n) acc[m][n] = z4;

  for (int k0 = 0; k0 < K; k0 += 32) {
    __syncthreads();
#pragma unroll
    for (int i = 0; i < 2; ++i) {
      const int ch = i * 256 + tid;
      const int row = ch >> 2, cc = (ch & 3) * 8;
      gload_lds16(A + (size_t)(tM + row) * K + k0 + cc, As + (size_t)(i * 256 + w * 64) * 8);
    }
    gload_lds16(W + (size_t)(tN + (tid >> 2)) * K + k0 + (tid & 3) * 8, Bs + (size_t)(w * 64) * 8);
    __syncthreads();
    bf16x8 af[2], bw[4];
#pragma unroll
    for (int m = 0; m < 2; ++m)
      af[m] = *(const bf16x8*)&As[(w * 32 + m * 16 + lr) * 32 + lg * 8];
#pragma unroll
    for (int n = 0; n < 4; ++n)
      bw[n] = *(const bf16x8*)&Bs[(n * 16 + lr) * 32 + lg * 8];
#pragma unroll
    for (int m = 0; m < 2; ++m)
#pragma unroll
      for (int n = 0; n < 4; ++n)
        acc[m][n] = __builtin_amdgcn_mfma_f32_16x16x32_bf16(af[m], bw[n], acc[m][n], 0, 0, 0);
  }

#pragma unroll
  for (int n = 0; n < 4; ++n) {
    const int col = tN + n * 16 + lr;
    const float bv = bias[col];
#pragma unroll
    for (int m = 0; m < 2; ++m)
#pragma unroll
      for (int r = 0; r < 4; ++r) {
        const int row = tM + w * 32 + m * 16 + lg * 4 + r;
        outf[(size_t)row * N + col] = acc[m][n][r] + bv;
      }
  }
}

// Flash attention, 32x32x16 MFMA, in-register P, zero-shift softmax (linear
// in kv -> kv-splittable). Block = 4 waves = (q-sub x kv-half), QBLK=64,
// KVB=32, two independent double-buffered kv streams (LDS 32KB). Grid 1024
// -> 4 blocks/CU -> 16 waves/CU. Epilogue: half-1 waves dump partial (O,l)
// into dead K/V LDS; half-0 waves add, normalize, store. bh in low 5 bits
// keeps each (b,h)'s K/V on one XCD's L2.
__global__ __launch_bounds__(256, 4)
void attn_fwd(const u16* __restrict__ qb, const u16* __restrict__ kb,
              const u16* __restrict__ vtb, u16* __restrict__ ob)
{
  __shared__ __align__(16) u16 smem[16384];   // 32 KB

  const int tid = threadIdx.x;
  const int w = tid >> 6, l = tid & 63;
  const int q32 = l & 31, hi = l >> 5;
  const int qs = w & 1, h = w >> 1;
  const int idx = blockIdx.x;
  const int bh = idx & 31, qblk = idx >> 5;
  const int bb = bh >> 4, hh = bh & 15;
  const int q0 = qblk * 64 + qs * 32;

  // Q (B-operand): lane holds Q[q0+q32][ks*16 + hi*8 + j]
  bf16x8 qf[4];
#pragma unroll
  for (int ks = 0; ks < 4; ++ks)
    qf[ks] = *(const bf16x8*)&qb[((size_t)bh * S_ + q0 + q32) * HD_ + ks * 16 + hi * 8];

  const f32x16 z16 = {};
  f32x16 acc[2] = {z16, z16};   // O^T partial over this wave's kv half
  float lrun = 0.f;

  // --- staging constants (pre-swizzled global source -> linear LDS dest) ---
  // K tile [32 kv][64 d] (128B rows): slot8 = c ^ (r&7) ^ ((r&16)>>2)
  // V tile [64 d][32 kv] ( 64B rows): slot4 = c ^ ((r>>1)&3) ^ ((r&16)>>3)
  const u16* ksrc0; const u16* ksrc1; const u16* vsrc0; const u16* vsrc1;
  int kd0, kd1, vd0, vd1;
  {
    const int r0 = qs * 16 + (l >> 3), r1 = r0 + 8;
    const int s0 = (l & 7) ^ (r0 & 7) ^ ((r0 & 16) >> 2);
    const int s1 = (l & 7) ^ (r1 & 7) ^ ((r1 & 16) >> 2);
    ksrc0 = kb + ((size_t)bh * S_ + r0) * HD_ + s0 * 8;
    ksrc1 = kb + ((size_t)bh * S_ + r1) * HD_ + s1 * 8;
    kd0 = (qs * 16) * 64; kd1 = (qs * 16 + 8) * 64;
    const int rv0 = qs * 32 + (l >> 2), rv1 = rv0 + 16;
    const int t0 = (l & 3) ^ ((rv0 >> 1) & 3) ^ ((rv0 & 16) >> 3);
    const int t1 = (l & 3) ^ ((rv1 >> 1) & 3) ^ ((rv1 & 16) >> 3);
    vsrc0 = vtb + ((size_t)bh * HD_ + rv0) * S_ + t0 * 8;
    vsrc1 = vtb + ((size_t)bh * HD_ + rv1) * S_ + t1 * 8;
    vd0 = (qs * 32) * 32; vd1 = (qs * 32 + 16) * 32;
  }
  const int kvbase = h * 1024;
  const int ktb0 = h * 4096;          // u16 offset of this stream's K bufs
  const int vtb0 = 8192 + h * 4096;   // V bufs

  auto STAGE = [&](int buf, int t) {
    const int kv0 = kvbase + t * KVB;
    u16* Kt = smem + ktb0 + buf * 2048;
    u16* Vt = smem + vtb0 + buf * 2048;
    gload_lds16(ksrc0 + (size_t)kv0 * HD_, Kt + kd0);
    gload_lds16(ksrc1 + (size_t)kv0 * HD_, Kt + kd1);
    gload_lds16(vsrc0 + kv0, Vt + vd0);
    gload_lds16(vsrc1 + kv0, Vt + vd1);
  };

  STAGE(0, 0);
  __syncthreads();

  const int rsK = (q32 & 7) ^ ((q32 & 16) >> 2);
  const int rsV = ((q32 >> 1) & 3) ^ ((q32 & 16) >> 3);

  for (int t = 0; t < 32; ++t) {
    const int cur = t & 1;
    if (t + 1 < 32) STAGE(cur ^ 1, t + 1);
    const u16* Kt = smem + ktb0 + cur * 2048;
    const u16* Vt = smem + vtb0 + cur * 2048;

    // QK^T: st = S^T[kv 32][q 32]
    f32x16 st = z16;
    __builtin_amdgcn_s_setprio(1);
#pragma unroll
    for (int ks = 0; ks < 4; ++ks) {
      const bf16x8 kf = *(const bf16x8*)&Kt[q32 * 64 + (((ks * 2 + hi) ^ rsK) << 3)];
      st = __builtin_amdgcn_mfma_f32_32x32x16_bf16(kf, qf[ks], st, 0, 0, 0);
    }
    __builtin_amdgcn_s_setprio(0);

    // softmax (p = 2^s) + pack + permlane32_swap -> PV B-operand frags
    float p[16];
#pragma unroll
    for (int r = 0; r < 16; ++r) p[r] = ex2(st[r]);
#pragma unroll
    for (int g = 0; g < 4; ++g)
      lrun += (p[4 * g] + p[4 * g + 1]) + (p[4 * g + 2] + p[4 * g + 3]);
    u32 wk0[4], wk1[4];
#pragma unroll
    for (int g = 0; g < 4; ++g) {
      wk0[g] = cvtpk(p[4 * g], p[4 * g + 1]);
      wk1[g] = cvtpk(p[4 * g + 2], p[4 * g + 3]);
    }
    bf16x8 pa[2];
#pragma unroll
    for (int k2 = 0; k2 < 2; ++k2) {
      u32 a0 = wk0[2 * k2], b0 = wk0[2 * k2 + 1];
      u32 a1 = wk1[2 * k2], b1 = wk1[2 * k2 + 1];
      asm volatile("v_permlane32_swap_b32 %0, %1" : "+v"(a0), "+v"(b0));
      asm volatile("v_permlane32_swap_b32 %0, %1" : "+v"(a1), "+v"(b1));
      uint4 wv = {a0, a1, b0, b1};
      pa[k2] = __builtin_bit_cast(bf16x8, wv);
    }

    // PV: acc[dt] += V^T-frag x pa -> O^T[d][q]
    __builtin_amdgcn_s_setprio(1);
#pragma unroll
    for (int dt = 0; dt < 2; ++dt)
#pragma unroll
      for (int k2 = 0; k2 < 2; ++k2) {
        const bf16x8 vf = *(const bf16x8*)&Vt[(dt * 32 + q32) * 32 + (((k2 * 2 + hi) ^ rsV) << 3)];
        acc[dt] = __builtin_amdgcn_mfma_f32_32x32x16_bf16(vf, pa[k2], acc[dt], 0, 0, 0);
      }
    __builtin_amdgcn_s_setprio(0);

    __syncthreads();
  }

  // ---- combine kv halves ----
  lrun += __shfl_xor(lrun, 32);
  __syncthreads();                       // K/V buffers now dead
  float* slice = (float*)smem + qs * 2112;
  if (h == 1) {
#pragma unroll
    for (int dt = 0; dt < 2; ++dt)
#pragma unroll
      for (int g = 0; g < 4; ++g) {
        f32x4 v = {acc[dt][4 * g], acc[dt][4 * g + 1], acc[dt][4 * g + 2], acc[dt][4 * g + 3]};
        *(f32x4*)&slice[q32 * 64 + dt * 32 + g * 8 + hi * 4] = v;
      }
    if (hi == 0) slice[2048 + q32] = lrun;
  }
  __syncthreads();
  if (h == 0) {
#pragma unroll
    for (int dt = 0; dt < 2; ++dt)
#pragma unroll
      for (int g = 0; g < 4; ++g) {
        const f32x4 v = *(const f32x4*)&slice[q32 * 64 + dt * 32 + g * 8 + hi * 4];
        acc[dt][4 * g]     += v.x;
        acc[dt][4 * g + 1] += v.y;
        acc[dt][4 * g + 2] += v.z;
        acc[dt][4 * g + 3] += v.w;
      }
    lrun += slice[2048 + q32];
    const float linv = 1.f / lrun;
    const size_t orow = ((size_t)(bb * S_ + q0 + q32)) * H_ + hh * HD_;
#pragma unroll
    for (int dt = 0; dt < 2; ++dt)
#pragma unroll
      for (int g = 0; g < 4; ++g) {
        const u32 o0 = cvtpk(acc[dt][4 * g] * linv, acc[dt][4 * g + 1] * linv);
        const u32 o1 = cvtpk(acc[dt][4 * g + 2] * linv, acc[dt][4 * g + 3] * linv);
        uint2 ov; ov.x = o0; ov.y = o1;
        *(uint2*)&ob[orow + dt * 32 + g * 8 + hi * 4] = ov;
      }
  }
}

extern "C" void kernel_launch(void* const* d_in, const int* in_sizes, int n_in,
                              void* d_out, int out_size, void* d_ws, size_t ws_size,
                              hipStream_t stream) {
  const float* x     = (const float*)d_in[0];
  const float* qkv_w = (const float*)d_in[1];
  const float* qkv_b = (const float*)d_in[2];
  const float* out_w = (const float*)d_in[3];
  const float* out_b = (const float*)d_in[4];

  char* ws = (char*)d_ws;
  u16* xb    = (u16*)(ws);
  u16* wqkvb = (u16*)(ws + 8388608);
  u16* wob   = (u16*)(ws + 14680064);
  u16* qb    = (u16*)(ws + 16777216);
  u16* kb    = (u16*)(ws + 25165824);
  u16* vtb   = (u16*)(ws + 33554432);   // V transposed: [b,h,d,s]
  u16* ob    = (u16*)(ws + 41943040);

  cvt_all<<<8192, 256, 0, stream>>>(x, qkv_w, out_w, xb, wqkvb, wob);

  gemm_qkv<<<dim3(24, 32), 256, 0, stream>>>(xb, wqkvb, qkv_b,
                                             qb, kb, vtb, 4096, 3072, 1024);
  attn_fwd<<<1024, 256, 0, stream>>>(qb, kb, vtb, ob);
  gemm_out<<<dim3(16, 32), 256, 0, stream>>>(ob, wob, out_b, (float*)d_out,
                                             4096, 1024, 1024);
}